// Round 16
// baseline (777.474 us; speedup 1.0000x reference)
//
#include <hip/hip_runtime.h>
#include <hip/hip_bf16.h>
#include <math.h>

// Problem constants (B=8, H=W=256, K=11 taps, thresh 0.2)
#define HH 256
#define WW 256
#define HW (HH*WW)
#define BB 8

typedef __hip_bfloat16 bf16;
typedef __attribute__((ext_vector_type(8))) short short8;    // 8 bf16 (4 VGPRs)
typedef __attribute__((ext_vector_type(4))) float f32x4;     // 16x16 MFMA acc
typedef __attribute__((ext_vector_type(16))) float f32x16;   // 32x32 MFMA acc

#define AS1 __attribute__((address_space(1)))
#define AS3 __attribute__((address_space(3)))

// v15 = best-of-measured consolidation:
// - conv128 layers: REVERT to v12 inner (747.7us config; v14's interior-row
//   cache was neutral-to-worse -> dropped per rigor rules).
// - conv64 layers: v13 dy-reuse cache (measured good).
// - head: lane-major B (measured good).
// - NEW: conv1 z-merge (COC=64, z=1): the old z=4 launch re-read the same
//   4-ch input window 4x and redid the 9-pt gather 4x. One block now
//   computes all 64 outputs: 1/4 input traffic, 1/4 blocks, same FLOPs.

// ---------------------------------------------------------------------------
// Weight reorder: OIHW f32 -> lane-major [kc][t][ks][nt][lane][8] bf16.
// ---------------------------------------------------------------------------
template<int CO, int CI>
__global__ __launch_bounds__(256) void reorder_w_cl(const float* __restrict__ w,
                                                    bf16* __restrict__ wr)
{
    int idx = blockIdx.x * 256 + threadIdx.x;
    if (idx >= 9 * CO * CI) return;
    int j    = idx & 7;
    int lane = (idx >> 3) & 63;
    int nt   = (idx >> 9) % (CO / 32);
    int rest = idx / (512 * (CO / 32));      // = (kc*9 + t)*2 + ks
    int ks   = rest & 1;
    int tt   = (rest >> 1) % 9;
    int kc   = rest / 18;
    int co = nt * 32 + (lane & 31);
    int ci = kc * 32 + ks * 16 + (lane >> 5) * 8 + j;
    wr[idx] = __float2bfloat16(w[((size_t)co * CI + ci) * 9 + tt]);
}

// Head weights -> lane-major [kc(2)][t(9)][fr(2)][lane(64)][8] bf16.
__global__ __launch_bounds__(256) void reorder_w_head2_lm(const float* __restrict__ wh,
                                                          const float* __restrict__ wv,
                                                          bf16* __restrict__ wr)
{
    int idx = blockIdx.x * 256 + threadIdx.x;
    if (idx >= 2 * 9 * 2 * 64 * 8) return;   // 18432
    int j    = idx & 7;
    int lane = (idx >> 3) & 63;
    int fr   = (idx >> 9) & 1;
    int t    = (idx >> 10) % 9;
    int kc   = (idx >> 10) / 9;
    int co   = fr * 16 + (lane & 15);
    int ci   = kc * 32 + (lane >> 4) * 8 + j;
    const float* src = (co < 16) ? wh : wv;
    int c = co & 15;
    float v = (c < 11) ? src[((size_t)c * 64 + ci) * 9 + t] : 0.0f;
    wr[idx] = __float2bfloat16(v);
}

// ---------------------------------------------------------------------------
// One-time zero of the OOB halo slots of BOTH slab buffers.
// ---------------------------------------------------------------------------
template<int ROWS, int TPB>
__device__ __forceinline__ void zero_oob(bf16* __restrict__ s0,
                                         bf16* __restrict__ s1,
                                         int tid, int x0, int y0)
{
    constexpr int UNITS = (ROWS + 2) * 264;      // 16B units per buffer
    const short8 z8 = {0,0,0,0,0,0,0,0};
    for (int e = tid; e < UNITS; e += TPB) {
        int row = e / 264, rem = e - row * 264;
        int px = rem >> 2;
        int yy = y0 - 1 + row, xx = x0 - 1 + px;
        if (yy < 0 || yy >= HH || xx < 0 || xx >= WW) {
            *(short8*)(s0 + (size_t)e * 8) = z8;
            *(short8*)(s1 + (size_t)e * 8) = z8;
        }
    }
}

// ---------------------------------------------------------------------------
// Async DMA staging of one 32-ch chunk: global_load_lds, 16 B/lane.
// ---------------------------------------------------------------------------
template<int CIN, int ROWS, int TPB>
__device__ __forceinline__ void stage_async(const bf16* __restrict__ in_i,
                                            bf16* __restrict__ slab,
                                            int tid, int x0, int y0, int k0)
{
    constexpr int UNITS = (ROWS + 2) * 264;
    const int lane = tid & 63;
    const int wb   = tid - lane;                 // wave's base unit
    for (int base = wb; base < UNITS; base += TPB) {
        int e = base + lane;
        int row = e / 264, rem = e - row * 264;
        int px = rem >> 2, slot = rem & 3;
        int seg = slot ^ ((px >> 1) & 3);
        int yy = y0 - 1 + row, xx = x0 - 1 + px;
        bool ok = (e < UNITS) && (yy >= 0) && (yy < HH) && (xx >= 0) && (xx < WW);
        if (ok) {
            const bf16* g = in_i + ((size_t)(yy * WW + xx)) * CIN + k0 + seg * 8;
            __builtin_amdgcn_global_load_lds((const AS1 void*)g,
                                             (AS3 void*)(slab + (size_t)base * 8),
                                             16, 0, 0);
        }
    }
}

// ---------------------------------------------------------------------------
// conv1: 3x3 conv over concat(rgb,depth) [4ch f32 planar], ReLU,
// output NHWC bf16 [G][HW][64]. Single z-group computes ALL 64 outputs.
// ---------------------------------------------------------------------------
template<int COC>
__global__ __launch_bounds__(256) void conv3x3_first(const float* __restrict__ rgb,
                                                     const float* __restrict__ depth,
                                                     const float* __restrict__ w,
                                                     const float* __restrict__ bias,
                                                     bf16* __restrict__ out, int b0)
{
    const int tid = threadIdx.x;
    const int img = blockIdx.y >> 6;
    const int b   = b0 + img;
    const int x = blockIdx.x * 64 + (tid & 63);
    const int y = (blockIdx.y & 63) * 4 + (tid >> 6);

    const bool vy0 = (y > 0), vy2 = (y < HH - 1);
    const bool vx0 = (x > 0), vx2 = (x < WW - 1);
    bool val[9];
    int  off[9];
    {
        int t = 0;
        for (int dy = -1; dy <= 1; ++dy)
            for (int dx = -1; dx <= 1; ++dx) {
                val[t] = (dy < 0 ? vy0 : (dy > 0 ? vy2 : true)) &&
                         (dx < 0 ? vx0 : (dx > 0 ? vx2 : true));
                off[t] = dy * WW + dx;
                ++t;
            }
    }

    float acc[COC];
#pragma unroll
    for (int j = 0; j < COC; ++j) acc[j] = bias[j];

    const int p0 = y * WW + x;
#pragma unroll
    for (int ci = 0; ci < 4; ++ci) {
        const float* p = (ci < 3) ? (rgb + ((size_t)(b * 3 + ci)) * HW + p0)
                                  : (depth + (size_t)b * HW + p0);
        float v[9];
#pragma unroll
        for (int t = 0; t < 9; ++t)
            v[t] = val[t] ? p[off[t]] : 0.0f;

        const float* wp = w + (size_t)ci * 9;
#pragma unroll
        for (int j = 0; j < COC; ++j) {
            const float* wj = wp + (size_t)j * 4 * 9;
#pragma unroll
            for (int t = 0; t < 9; ++t)
                acc[j] = fmaf(wj[t], v[t], acc[j]);
        }
    }

    // vectorized bf16 store: COC=64 -> eight short8 (16B each, aligned)
    bf16* op = out + (size_t)img * HW * 64 + (size_t)p0 * 64;
#pragma unroll
    for (int g = 0; g < COC / 8; ++g) {
        short8 s;
#pragma unroll
        for (int j = 0; j < 8; ++j) {
            bf16 h = __float2bfloat16(fmaxf(acc[g * 8 + j], 0.0f));
            s[j] = *reinterpret_cast<short*>(&h);
        }
        *(short8*)(op + g * 8) = s;
    }
}

// ---------------------------------------------------------------------------
// MFMA implicit-GEMM 3x3 conv v12 (COUT=128 layers, 747.7us-verified):
// dbuf staging, 1 barrier/chunk, 4 waves = 2 row-pairs x 2 co-halves,
// mt4 x NTT, 32x32x16, lane-major coalesced B.
// ---------------------------------------------------------------------------
template<int CIN, int COUT, int WPB>
__global__ __launch_bounds__(256, WPB) void conv_mfma_v12(const bf16* __restrict__ in,
                                                          const bf16* __restrict__ wrb,
                                                          const float* __restrict__ bias,
                                                          bf16* __restrict__ out)
{
    constexpr int NCH  = CIN / 32;
    constexpr int NTT  = COUT / 64;
    constexpr int NTOT = COUT / 32;
    constexpr int SLAB = 6 * 66 * 32;
    __shared__ bf16 slab[2 * SLAB];

    const int tid  = threadIdx.x;
    const int lane = tid & 63;
    const int wv   = tid >> 6;
    const int ng   = wv & 1;
    const int rg   = wv >> 1;
    const int ln31 = lane & 31;
    const int oct  = lane >> 5;
    const int img  = blockIdx.y >> 6;
    const int x0   = blockIdx.x * 64;
    const int y0   = (blockIdx.y & 63) * 4;

    const bf16* in_i  = in  + (size_t)img * HW * CIN;
    bf16*       out_i = out + (size_t)img * HW * COUT;

    f32x16 acc[4][NTT];
#pragma unroll
    for (int mt = 0; mt < 4; ++mt)
#pragma unroll
        for (int nt = 0; nt < NTT; ++nt)
#pragma unroll
            for (int j = 0; j < 16; ++j) acc[mt][nt][j] = 0.0f;

    zero_oob<4, 256>(slab, slab + SLAB, tid, x0, y0);
    stage_async<CIN, 4, 256>(in_i, slab, tid, x0, y0, 0);

    int cur = 0;
    for (int kc = 0; kc < NCH; ++kc) {
        __syncthreads();
        if (kc + 1 < NCH)
            stage_async<CIN, 4, 256>(in_i, slab + (size_t)(cur ^ 1) * SLAB,
                                     tid, x0, y0, (kc + 1) * 32);

        const bf16* sb = slab + (size_t)cur * SLAB;
#pragma unroll
        for (int t = 0; t < 9; ++t) {
            const int dy = t / 3 - 1, dx = t % 3 - 1;
#pragma unroll
            for (int ks = 0; ks < 2; ++ks) {
                short8 a[4];
#pragma unroll
                for (int mt = 0; mt < 4; ++mt) {
                    const int srow = 2 * rg + (mt >> 1) + dy + 1;      // 0..5
                    const int px   = (mt & 1) * 32 + ln31 + dx + 1;    // 0..65
                    const int slot = (ks * 2 + oct) ^ ((px >> 1) & 3);
                    a[mt] = *(const short8*)(sb + (srow * 66 + px) * 32 + slot * 8);
                }
#pragma unroll
                for (int nt = 0; nt < NTT; ++nt) {
                    const int gnt = ng * NTT + nt;
                    short8 bfr = *(const short8*)(wrb
                        + ((size_t)((((kc * 9 + t) * 2 + ks) * NTOT + gnt) * 64 + lane)) * 8);
#pragma unroll
                    for (int mt = 0; mt < 4; ++mt)
                        acc[mt][nt] = __builtin_amdgcn_mfma_f32_32x32x16_bf16(
                                          a[mt], bfr, acc[mt][nt], 0, 0, 0);
                }
            }
        }
        cur ^= 1;
    }

    // Epilogue. 32x32 C/D: col(co) = lane&31, row(px) = (j&3)+8*(j>>2)+4*oct.
#pragma unroll
    for (int nt = 0; nt < NTT; ++nt) {
        const int co = (ng * NTT + nt) * 32 + ln31;
        const float bb = bias[co];
#pragma unroll
        for (int mt = 0; mt < 4; ++mt) {
            const int r  = 2 * rg + (mt >> 1);
            const int xb = x0 + (mt & 1) * 32;
#pragma unroll
            for (int j = 0; j < 16; ++j) {
                const int m = (j & 3) + 8 * (j >> 2) + 4 * oct;
                const float v = fmaxf(acc[mt][nt][j] + bb, 0.0f);
                out_i[((size_t)(y0 + r) * WW + (xb + m)) * COUT + co] = __float2bfloat16(v);
            }
        }
    }
}

// ---------------------------------------------------------------------------
// conv v13 (COUT=64 layers, measured good): dy-reuse full af[4][2] cache.
// ---------------------------------------------------------------------------
template<int CIN, int COUT, int WPB>
__global__ __launch_bounds__(256, WPB) void conv_mfma_v13(const bf16* __restrict__ in,
                                                          const bf16* __restrict__ wrb,
                                                          const float* __restrict__ bias,
                                                          bf16* __restrict__ out)
{
    constexpr int NCH  = CIN / 32;
    constexpr int NTT  = COUT / 64;          // 1 for COUT=64
    constexpr int NTOT = COUT / 32;
    constexpr int SLAB = 6 * 66 * 32;
    __shared__ bf16 slab[2 * SLAB];

    const int tid  = threadIdx.x;
    const int lane = tid & 63;
    const int wv   = tid >> 6;
    const int ng   = wv & 1;
    const int rg   = wv >> 1;
    const int ln31 = lane & 31;
    const int oct  = lane >> 5;
    const int img  = blockIdx.y >> 6;
    const int x0   = blockIdx.x * 64;
    const int y0   = (blockIdx.y & 63) * 4;

    const bf16* in_i  = in  + (size_t)img * HW * CIN;
    bf16*       out_i = out + (size_t)img * HW * COUT;

    f32x16 acc[4][NTT];
#pragma unroll
    for (int mt = 0; mt < 4; ++mt)
#pragma unroll
        for (int nt = 0; nt < NTT; ++nt)
#pragma unroll
            for (int j = 0; j < 16; ++j) acc[mt][nt][j] = 0.0f;

    zero_oob<4, 256>(slab, slab + SLAB, tid, x0, y0);
    stage_async<CIN, 4, 256>(in_i, slab, tid, x0, y0, 0);

    int cur = 0;
    for (int kc = 0; kc < NCH; ++kc) {
        __syncthreads();
        if (kc + 1 < NCH)
            stage_async<CIN, 4, 256>(in_i, slab + (size_t)(cur ^ 1) * SLAB,
                                     tid, x0, y0, (kc + 1) * 32);

        const bf16* sb = slab + (size_t)cur * SLAB;
#pragma unroll
        for (int dxi = 0; dxi < 3; ++dxi) {
            const int dx = dxi - 1;
#pragma unroll
            for (int ks = 0; ks < 2; ++ks) {
                short8 af[4][2];             // [srow offset][x-half]
#pragma unroll
                for (int s = 0; s < 4; ++s)
#pragma unroll
                    for (int mx = 0; mx < 2; ++mx) {
                        const int px   = mx * 32 + ln31 + dx + 1;
                        const int slot = (ks * 2 + oct) ^ ((px >> 1) & 3);
                        af[s][mx] = *(const short8*)(sb + ((2 * rg + s) * 66 + px) * 32 + slot * 8);
                    }
#pragma unroll
                for (int dyi = 0; dyi < 3; ++dyi) {
                    const int t = dyi * 3 + dxi;
#pragma unroll
                    for (int nt = 0; nt < NTT; ++nt) {
                        const int gnt = ng * NTT + nt;
                        short8 bfr = *(const short8*)(wrb
                            + ((size_t)((((kc * 9 + t) * 2 + ks) * NTOT + gnt) * 64 + lane)) * 8);
#pragma unroll
                        for (int mt = 0; mt < 4; ++mt)
                            acc[mt][nt] = __builtin_amdgcn_mfma_f32_32x32x16_bf16(
                                              af[(mt >> 1) + dyi][mt & 1], bfr, acc[mt][nt], 0, 0, 0);
                    }
                }
            }
        }
        cur ^= 1;
    }

#pragma unroll
    for (int nt = 0; nt < NTT; ++nt) {
        const int co = (ng * NTT + nt) * 32 + ln31;
        const float bb = bias[co];
#pragma unroll
        for (int mt = 0; mt < 4; ++mt) {
            const int r  = 2 * rg + (mt >> 1);
            const int xb = x0 + (mt & 1) * 32;
#pragma unroll
            for (int j = 0; j < 16; ++j) {
                const int m = (j & 3) + 8 * (j >> 2) + 4 * oct;
                const float v = fmaxf(acc[mt][nt][j] + bb, 0.0f);
                out_i[((size_t)(y0 + r) * WW + (xb + m)) * COUT + co] = __float2bfloat16(v);
            }
        }
    }
}

// ---------------------------------------------------------------------------
// Merged heads: dbuf DMA staging, both kh and kv; lane-major coalesced B;
// per-pixel softmax over 11 channels via wave-private padded LDS transpose.
// ---------------------------------------------------------------------------
__global__ __launch_bounds__(256, 2) void head_mfma2(const bf16* __restrict__ in,
                                                     const bf16* __restrict__ wrp,
                                                     const float* __restrict__ bh,
                                                     const float* __restrict__ bv,
                                                     float* __restrict__ kh_base,
                                                     float* __restrict__ kv_base,
                                                     int b0)
{
    constexpr int SLABH = 6 * 66 * 32;
    __shared__ bf16  slab[2 * SLABH];       // 50,688 B
    __shared__ float smx[4][64][17];        // 17,408 B (wave-private slices)

    const int tid  = threadIdx.x;
    const int lane = tid & 63;
    const int wv   = tid >> 6;
    const int m    = lane & 15;
    const int q    = lane >> 4;
    const int img  = blockIdx.y >> 6;
    const int x0   = blockIdx.x * 64;
    const int y0   = (blockIdx.y & 63) * 4;
    const int y    = y0 + wv;

    const bf16* in_i = in + (size_t)img * HW * 64;

    f32x4 acc[4][2];
#pragma unroll
    for (int f = 0; f < 4; ++f) { acc[f][0] = (f32x4){0.f,0.f,0.f,0.f}; acc[f][1] = (f32x4){0.f,0.f,0.f,0.f}; }

    zero_oob<4, 256>(slab, slab + SLABH, tid, x0, y0);
    stage_async<64, 4, 256>(in_i, slab, tid, x0, y0, 0);

    int cur = 0;
    for (int kc = 0; kc < 2; ++kc) {
        __syncthreads();
        if (kc == 0)
            stage_async<64, 4, 256>(in_i, slab + SLABH, tid, x0, y0, 32);

        const bf16* sb = slab + (size_t)cur * SLABH;
#pragma unroll
        for (int t = 0; t < 9; ++t) {
            const int dy = t / 3 - 1, dx = t % 3 - 1;
            const int srow = wv + dy + 1;
            // lane-major: [kc][t][fr][lane][8] — one contiguous 512B frag per load
            short8 b0f = *(const short8*)(wrp + ((size_t)(((kc * 9 + t) * 2 + 0) * 64 + lane)) * 8);
            short8 b1f = *(const short8*)(wrp + ((size_t)(((kc * 9 + t) * 2 + 1) * 64 + lane)) * 8);
#pragma unroll
            for (int f = 0; f < 4; ++f) {
                const int px = f * 16 + m + dx + 1;
                const int slot = q ^ ((px >> 1) & 3);
                short8 a = *(const short8*)(sb + (srow * 66 + px) * 32 + slot * 8);
                acc[f][0] = __builtin_amdgcn_mfma_f32_16x16x32_bf16(a, b0f, acc[f][0], 0, 0, 0);
                acc[f][1] = __builtin_amdgcn_mfma_f32_16x16x32_bf16(a, b1f, acc[f][1], 0, 0, 0);
            }
        }
        cur ^= 1;
    }

    // two heads sequentially; smx slice is wave-private (no barrier needed)
#pragma unroll
    for (int head = 0; head < 2; ++head) {
        const float* bias = head ? bv : bh;
        const float bb = (m < 11) ? bias[m] : 0.0f;
#pragma unroll
        for (int f = 0; f < 4; ++f)
#pragma unroll
            for (int r = 0; r < 4; ++r)
                smx[wv][f * 16 + q * 4 + r][m] = acc[f][head][r] + bb;

        float v[11];
#pragma unroll
        for (int j = 0; j < 11; ++j) v[j] = smx[wv][lane][j];
        float mx = v[0];
#pragma unroll
        for (int j = 1; j < 11; ++j) mx = fmaxf(mx, v[j]);
        float s = 0.0f;
#pragma unroll
        for (int j = 0; j < 11; ++j) { v[j] = expf(v[j] - mx); s += v[j]; }
        const float inv = 1.0f / s;

        float* op = (head ? kv_base : kh_base) + (size_t)(b0 + img) * 11 * HW
                    + (size_t)y * WW + x0 + lane;
#pragma unroll
        for (int j = 0; j < 11; ++j)
            op[(size_t)j * HW] = v[j] * inv;
    }
}

// ---------------------------------------------------------------------------
// Horizontal separable pass (full batch): h = sum_i kh_i * shift_x(rgb, i-5)
// ---------------------------------------------------------------------------
__global__ __launch_bounds__(256) void hpass(const float* __restrict__ rgb,
                                             const float* __restrict__ kh,
                                             float* __restrict__ h)
{
    int idx = blockIdx.x * 256 + threadIdx.x;     // b*HW + p, total 524288
    int b = idx >> 16;                            // HW = 2^16
    int p = idx & (HW - 1);
    int y = p >> 8;
    int x = p & 255;

    float kw[11];
#pragma unroll
    for (int i = 0; i < 11; ++i) kw[i] = kh[((size_t)(b * 11 + i)) * HW + p];

#pragma unroll
    for (int c = 0; c < 3; ++c) {
        const float* rp = rgb + ((size_t)(b * 3 + c)) * HW + (size_t)y * WW;
        float s = 0.0f;
#pragma unroll
        for (int i = 0; i < 11; ++i) {
            int xx = x + i - 5;
            if (xx >= 0 && xx < WW) s = fmaf(kw[i], rp[xx], s);
        }
        h[((size_t)(b * 3 + c)) * HW + p] = s;
    }
}

// ---------------------------------------------------------------------------
// Vertical pass + depth-mask composite. Writes final, blurred, mask.
// ---------------------------------------------------------------------------
__global__ __launch_bounds__(256) void vpass_compose(const float* __restrict__ h,
                                                     const float* __restrict__ kv,
                                                     const float* __restrict__ rgb,
                                                     const float* __restrict__ depth,
                                                     float* __restrict__ fin,
                                                     float* __restrict__ blur,
                                                     float* __restrict__ masko)
{
    int idx = blockIdx.x * 256 + threadIdx.x;
    int b = idx >> 16;                            // HW = 2^16
    int p = idx & (HW - 1);
    int y = p >> 8;
    int x = p & 255;

    float kw[11];
#pragma unroll
    for (int i = 0; i < 11; ++i) kw[i] = kv[((size_t)(b * 11 + i)) * HW + p];

    float d = depth[idx];
    float mk = (d > 0.2f) ? 1.0f : 0.0f;
    masko[idx] = mk;

#pragma unroll
    for (int c = 0; c < 3; ++c) {
        const float* hp = h + ((size_t)(b * 3 + c)) * HW + x;
        float s = 0.0f;
#pragma unroll
        for (int i = 0; i < 11; ++i) {
            int yy = y + i - 5;
            if (yy >= 0 && yy < HH) s = fmaf(kw[i], hp[(size_t)yy * WW], s);
        }
        size_t o = ((size_t)(b * 3 + c)) * HW + p;
        blur[o] = s;
        fin[o] = mk * rgb[o] + (1.0f - mk) * s;
    }
}

// ---------------------------------------------------------------------------
extern "C" void kernel_launch(void* const* d_in, const int* in_sizes, int n_in,
                              void* d_out, int out_size, void* d_ws, size_t ws_size,
                              hipStream_t stream)
{
    const float* rgb   = (const float*)d_in[0];
    const float* depth = (const float*)d_in[1];
    const float* w1 = (const float*)d_in[2];  const float* b1 = (const float*)d_in[3];
    const float* w2 = (const float*)d_in[4];  const float* b2 = (const float*)d_in[5];
    const float* w3 = (const float*)d_in[6];  const float* b3 = (const float*)d_in[7];
    const float* w4 = (const float*)d_in[8];  const float* b4 = (const float*)d_in[9];
    const float* w5 = (const float*)d_in[10]; const float* b5 = (const float*)d_in[11];
    const float* wh = (const float*)d_in[12]; const float* bh = (const float*)d_in[13];
    const float* wv = (const float*)d_in[14]; const float* bv = (const float*)d_in[15];

    float* out    = (float*)d_out;
    float* fin_o  = out;                    // [8,3,256,256]
    float* blur_o = out + 1572864;          // [8,3,256,256]
    float* kh_o   = out + 3145728;          // [8,11,256,256]
    float* kv_o   = out + 8912896;          // [8,11,256,256]
    float* mask_o = out + 14680064;         // [8,1,256,256]

    // --- Select batch group size G from ws_size (deterministic -> graph-safe).
    const size_t perG = (size_t)HW * 2 * (128 + 64 + 128);   // 41.9 MB per image
    const size_t wsz  = (size_t)1 * 1024 * 1024;
    int G = 1;
    if (ws_size >= 8 * perG + wsz) G = 8;
    else if (ws_size >= 4 * perG + wsz) G = 4;
    else if (ws_size >= 2 * perG + wsz) G = 2;

    char* ws = (char*)d_ws;
    const size_t szA = (size_t)G * HW * 128 * 2;
    const size_t szB = (size_t)G * HW * 64 * 2;
    const size_t szC = (size_t)G * HW * 128 * 2;
    bf16* bufA = (bf16*)ws;
    bf16* bufB = (bf16*)(ws + szA);
    bf16* bufC = (bf16*)(ws + szA + szB);
    float* hbuf = (float*)bufC;              // 6.3 MB <= szC

    bf16* w2r  = (bf16*)(ws + szA + szB + szC);
    bf16* w3r  = w2r + 9 * 64 * 64;
    bf16* w4r  = w3r + 9 * 128 * 64;
    bf16* w5r  = w4r + 9 * 128 * 128;
    bf16* whvr = w5r + 9 * 64 * 128;         // [2][9][2][64][8] lane-major

    dim3 blk(256);

    // one-time weight reorders (graph-safe: identical work every call)
    reorder_w_cl<64, 64>  <<<dim3((9*64*64   + 255) / 256), blk, 0, stream>>>(w2, w2r);
    reorder_w_cl<128, 64> <<<dim3((9*128*64  + 255) / 256), blk, 0, stream>>>(w3, w3r);
    reorder_w_cl<128, 128><<<dim3((9*128*128 + 255) / 256), blk, 0, stream>>>(w4, w4r);
    reorder_w_cl<64, 128> <<<dim3((9*64*128  + 255) / 256), blk, 0, stream>>>(w5, w5r);
    reorder_w_head2_lm    <<<dim3((18432     + 255) / 256), blk, 0, stream>>>(wh, wv, whvr);

    for (int b0 = 0; b0 < BB; b0 += G) {
        // conv1: single z-group computes all 64 outputs (1/4 input traffic).
        conv3x3_first<64><<<dim3(4, 64 * G, 1), blk, 0, stream>>>(rgb, depth, w1, b1, bufA, b0);
        // COUT=64: v13 (dy-reuse cache); COUT=128: v12 (747.7us-verified).
        conv_mfma_v13<64, 64, 3>  <<<dim3(4, 64 * G), blk, 0, stream>>>(bufA, w2r, b2, bufB);
        conv_mfma_v12<64, 128, 2> <<<dim3(4, 64 * G), blk, 0, stream>>>(bufB, w3r, b3, bufC);
        conv_mfma_v12<128, 128, 2><<<dim3(4, 64 * G), blk, 0, stream>>>(bufC, w4r, b4, bufA);
        conv_mfma_v13<128, 64, 3> <<<dim3(4, 64 * G), blk, 0, stream>>>(bufA, w5r, b5, bufB);
        head_mfma2<<<dim3(4, 64 * G), blk, 0, stream>>>(bufB, whvr, bh, bv, kh_o, kv_o, b0);
    }

    // separable blur + composite (full batch; bufC conv use dead by now)
    hpass<<<dim3(2048), blk, 0, stream>>>(rgb, kh_o, hbuf);
    vpass_compose<<<dim3(2048), blk, 0, stream>>>(hbuf, kv_o, rgb, depth,
                                                  fin_o, blur_o, mask_o);
}

// Round 17
// 647.066 us; speedup vs baseline: 1.2015x; 1.2015x over previous
//
#include <hip/hip_runtime.h>
#include <hip/hip_bf16.h>
#include <math.h>

// Problem constants (B=8, H=W=256, K=11 taps, thresh 0.2)
#define HH 256
#define WW 256
#define HW (HH*WW)
#define BB 8
#define PW 258
#define PHW2 (PW*PW)   // 66564, padded pixel count for conv1 input

typedef __hip_bfloat16 bf16;
typedef __attribute__((ext_vector_type(8))) short short8;    // 8 bf16 (4 VGPRs)
typedef __attribute__((ext_vector_type(4))) float f32x4;     // 16x16 MFMA acc
typedef __attribute__((ext_vector_type(16))) float f32x16;   // 32x32 MFMA acc

#define AS1 __attribute__((address_space(1)))
#define AS3 __attribute__((address_space(3)))

// v16 = round-14 best config (747.7us: v13 conv64 + v12 conv128 + lane-major
// head) + MFMA conv1. Round-16 counters showed scalar conv1 is ~150-180us
// (VALU-bound on 1:1 weight-load:FMA; 10x off its 15us VALU floor).
// New conv1: pad8 pre-pass (rgbd f32 -> halo-padded NHWC bf16 [258^2][8],
// ch 4-7 zero; aliases bufC which is dead during conv1) + conv1_mfma
// (5x mfma_32x32x16, k-group km = taps {2km,2km+1}; A-frag = ONE 16B load
// pad8[y+dy][px+dx][0..8) with tap chosen by lane oct; B prepacked
// lane-major with tap-9 slot zeroed so K=36->80 padding is free).

// ---------------------------------------------------------------------------
// Weight reorder: OIHW f32 -> lane-major [kc][t][ks][nt][lane][8] bf16.
// ---------------------------------------------------------------------------
template<int CO, int CI>
__global__ __launch_bounds__(256) void reorder_w_cl(const float* __restrict__ w,
                                                    bf16* __restrict__ wr)
{
    int idx = blockIdx.x * 256 + threadIdx.x;
    if (idx >= 9 * CO * CI) return;
    int j    = idx & 7;
    int lane = (idx >> 3) & 63;
    int nt   = (idx >> 9) % (CO / 32);
    int rest = idx / (512 * (CO / 32));      // = (kc*9 + t)*2 + ks
    int ks   = rest & 1;
    int tt   = (rest >> 1) % 9;
    int kc   = rest / 18;
    int co = nt * 32 + (lane & 31);
    int ci = kc * 32 + ks * 16 + (lane >> 5) * 8 + j;
    wr[idx] = __float2bfloat16(w[((size_t)co * CI + ci) * 9 + tt]);
}

// Head weights -> lane-major [kc(2)][t(9)][fr(2)][lane(64)][8] bf16.
__global__ __launch_bounds__(256) void reorder_w_head2_lm(const float* __restrict__ wh,
                                                          const float* __restrict__ wv,
                                                          bf16* __restrict__ wr)
{
    int idx = blockIdx.x * 256 + threadIdx.x;
    if (idx >= 2 * 9 * 2 * 64 * 8) return;   // 18432
    int j    = idx & 7;
    int lane = (idx >> 3) & 63;
    int fr   = (idx >> 9) & 1;
    int t    = (idx >> 10) % 9;
    int kc   = (idx >> 10) / 9;
    int co   = fr * 16 + (lane & 15);
    int ci   = kc * 32 + (lane >> 4) * 8 + j;
    const float* src = (co < 16) ? wh : wv;
    int c = co & 15;
    float v = (c < 11) ? src[((size_t)c * 64 + ci) * 9 + t] : 0.0f;
    wr[idx] = __float2bfloat16(v);
}

// conv1 weights: OIHW f32 [64][4][3][3] -> [km(5)][nt(2)][lane(64)][8] bf16.
// k = km*16 + oct*8 + j -> tap = km*2+oct, ci = j; zero for tap>8 or ci>3.
__global__ __launch_bounds__(256) void reorder_w1_mfma(const float* __restrict__ w,
                                                       bf16* __restrict__ wr)
{
    int idx = blockIdx.x * 256 + threadIdx.x;
    if (idx >= 5 * 2 * 64 * 8) return;       // 5120
    int j    = idx & 7;
    int lane = (idx >> 3) & 63;
    int nt   = (idx >> 9) & 1;
    int km   = idx >> 10;
    int co   = nt * 32 + (lane & 31);
    int tap  = km * 2 + (lane >> 5);
    float v  = (tap < 9 && j < 4) ? w[((size_t)co * 4 + j) * 9 + tap] : 0.0f;
    wr[idx] = __float2bfloat16(v);
}

// ---------------------------------------------------------------------------
// pad8: rgbd f32 planar -> halo-padded NHWC bf16 [G][PHW2][8] (ch4-7 = 0,
// halo pixels = 0). One thread per padded pixel, one 16B store.
// ---------------------------------------------------------------------------
__global__ __launch_bounds__(256) void pad8_rgbd(const float* __restrict__ rgb,
                                                 const float* __restrict__ depth,
                                                 bf16* __restrict__ p8,
                                                 int b0, int G)
{
    int idx = blockIdx.x * 256 + threadIdx.x;
    if (idx >= G * PHW2) return;
    int img = idx / PHW2;
    int rem = idx - img * PHW2;
    int r = rem / PW, c = rem - r * PW;
    int y = r - 1, x = c - 1;
    short8 s = {0,0,0,0,0,0,0,0};
    if (y >= 0 && y < HH && x >= 0 && x < WW) {
        const int b = b0 + img;
        const int p0 = y * WW + x;
        float v[4];
        v[0] = rgb[((size_t)(b * 3 + 0)) * HW + p0];
        v[1] = rgb[((size_t)(b * 3 + 1)) * HW + p0];
        v[2] = rgb[((size_t)(b * 3 + 2)) * HW + p0];
        v[3] = depth[(size_t)b * HW + p0];
#pragma unroll
        for (int j = 0; j < 4; ++j) {
            bf16 h = __float2bfloat16(v[j]);
            s[j] = *reinterpret_cast<short*>(&h);
        }
    }
    *(short8*)(p8 + (size_t)idx * 8) = s;
}

// ---------------------------------------------------------------------------
// conv1_mfma: 3x3 conv over pad8 [G][PHW2][8] via 5x mfma_32x32x16.
// 4 waves = 4 rows; wave: mt(2) x nt(2), acc 64 AGPR; no LDS, no barriers.
// A-frag: pad8[y+dy(tap)+1][x0+mt*32+ln31+dx(tap)+1][0..8), tap = km*2+oct
// (tap 9 clamped to 8; its B block is zero). Output NHWC bf16 [G][HW][64].
// ---------------------------------------------------------------------------
__global__ __launch_bounds__(256, 3) void conv1_mfma(const bf16* __restrict__ p8,
                                                     const bf16* __restrict__ w1r,
                                                     const float* __restrict__ bias,
                                                     bf16* __restrict__ out)
{
    const int tid  = threadIdx.x;
    const int lane = tid & 63;
    const int wv   = tid >> 6;
    const int ln31 = lane & 31;
    const int oct  = lane >> 5;
    const int img  = blockIdx.y >> 6;
    const int x0   = blockIdx.x * 64;
    const int y    = (blockIdx.y & 63) * 4 + wv;

    const bf16* p8i   = p8  + (size_t)img * PHW2 * 8;
    bf16*       out_i = out + (size_t)img * HW * 64;

    f32x16 acc[2][2];
#pragma unroll
    for (int mt = 0; mt < 2; ++mt)
#pragma unroll
        for (int nt = 0; nt < 2; ++nt)
#pragma unroll
            for (int j = 0; j < 16; ++j) acc[mt][nt][j] = 0.0f;

#pragma unroll
    for (int km = 0; km < 5; ++km) {
        const int tap = km * 2 + oct;
        const int te  = (tap < 9) ? tap : 8;     // tap 9: B is zero, A harmless
        const int dy  = te / 3 - 1, dx = te % 3 - 1;
        short8 a[2];
#pragma unroll
        for (int mt = 0; mt < 2; ++mt) {
            const int px = x0 + mt * 32 + ln31 + dx + 1;
            a[mt] = *(const short8*)(p8i + ((size_t)(y + dy + 1) * PW + px) * 8);
        }
#pragma unroll
        for (int nt = 0; nt < 2; ++nt) {
            short8 bfr = *(const short8*)(w1r + ((size_t)((km * 2 + nt) * 64 + lane)) * 8);
#pragma unroll
            for (int mt = 0; mt < 2; ++mt)
                acc[mt][nt] = __builtin_amdgcn_mfma_f32_32x32x16_bf16(
                                  a[mt], bfr, acc[mt][nt], 0, 0, 0);
        }
    }

    // Epilogue. 32x32 C/D: col(co) = lane&31, row(px) = (j&3)+8*(j>>2)+4*oct.
#pragma unroll
    for (int nt = 0; nt < 2; ++nt) {
        const int co = nt * 32 + ln31;
        const float bb = bias[co];
#pragma unroll
        for (int mt = 0; mt < 2; ++mt) {
            const int xb = x0 + mt * 32;
#pragma unroll
            for (int j = 0; j < 16; ++j) {
                const int m = (j & 3) + 8 * (j >> 2) + 4 * oct;
                const float v = fmaxf(acc[mt][nt][j] + bb, 0.0f);
                out_i[((size_t)y * WW + (xb + m)) * 64 + co] = __float2bfloat16(v);
            }
        }
    }
}

// ---------------------------------------------------------------------------
// One-time zero of the OOB halo slots of BOTH slab buffers.
// ---------------------------------------------------------------------------
template<int ROWS, int TPB>
__device__ __forceinline__ void zero_oob(bf16* __restrict__ s0,
                                         bf16* __restrict__ s1,
                                         int tid, int x0, int y0)
{
    constexpr int UNITS = (ROWS + 2) * 264;      // 16B units per buffer
    const short8 z8 = {0,0,0,0,0,0,0,0};
    for (int e = tid; e < UNITS; e += TPB) {
        int row = e / 264, rem = e - row * 264;
        int px = rem >> 2;
        int yy = y0 - 1 + row, xx = x0 - 1 + px;
        if (yy < 0 || yy >= HH || xx < 0 || xx >= WW) {
            *(short8*)(s0 + (size_t)e * 8) = z8;
            *(short8*)(s1 + (size_t)e * 8) = z8;
        }
    }
}

// ---------------------------------------------------------------------------
// Async DMA staging of one 32-ch chunk: global_load_lds, 16 B/lane.
// ---------------------------------------------------------------------------
template<int CIN, int ROWS, int TPB>
__device__ __forceinline__ void stage_async(const bf16* __restrict__ in_i,
                                            bf16* __restrict__ slab,
                                            int tid, int x0, int y0, int k0)
{
    constexpr int UNITS = (ROWS + 2) * 264;
    const int lane = tid & 63;
    const int wb   = tid - lane;                 // wave's base unit
    for (int base = wb; base < UNITS; base += TPB) {
        int e = base + lane;
        int row = e / 264, rem = e - row * 264;
        int px = rem >> 2, slot = rem & 3;
        int seg = slot ^ ((px >> 1) & 3);
        int yy = y0 - 1 + row, xx = x0 - 1 + px;
        bool ok = (e < UNITS) && (yy >= 0) && (yy < HH) && (xx >= 0) && (xx < WW);
        if (ok) {
            const bf16* g = in_i + ((size_t)(yy * WW + xx)) * CIN + k0 + seg * 8;
            __builtin_amdgcn_global_load_lds((const AS1 void*)g,
                                             (AS3 void*)(slab + (size_t)base * 8),
                                             16, 0, 0);
        }
    }
}

// ---------------------------------------------------------------------------
// MFMA implicit-GEMM 3x3 conv v12 (COUT=128 layers, 747.7us-verified).
// ---------------------------------------------------------------------------
template<int CIN, int COUT, int WPB>
__global__ __launch_bounds__(256, WPB) void conv_mfma_v12(const bf16* __restrict__ in,
                                                          const bf16* __restrict__ wrb,
                                                          const float* __restrict__ bias,
                                                          bf16* __restrict__ out)
{
    constexpr int NCH  = CIN / 32;
    constexpr int NTT  = COUT / 64;
    constexpr int NTOT = COUT / 32;
    constexpr int SLAB = 6 * 66 * 32;
    __shared__ bf16 slab[2 * SLAB];

    const int tid  = threadIdx.x;
    const int lane = tid & 63;
    const int wv   = tid >> 6;
    const int ng   = wv & 1;
    const int rg   = wv >> 1;
    const int ln31 = lane & 31;
    const int oct  = lane >> 5;
    const int img  = blockIdx.y >> 6;
    const int x0   = blockIdx.x * 64;
    const int y0   = (blockIdx.y & 63) * 4;

    const bf16* in_i  = in  + (size_t)img * HW * CIN;
    bf16*       out_i = out + (size_t)img * HW * COUT;

    f32x16 acc[4][NTT];
#pragma unroll
    for (int mt = 0; mt < 4; ++mt)
#pragma unroll
        for (int nt = 0; nt < NTT; ++nt)
#pragma unroll
            for (int j = 0; j < 16; ++j) acc[mt][nt][j] = 0.0f;

    zero_oob<4, 256>(slab, slab + SLAB, tid, x0, y0);
    stage_async<CIN, 4, 256>(in_i, slab, tid, x0, y0, 0);

    int cur = 0;
    for (int kc = 0; kc < NCH; ++kc) {
        __syncthreads();
        if (kc + 1 < NCH)
            stage_async<CIN, 4, 256>(in_i, slab + (size_t)(cur ^ 1) * SLAB,
                                     tid, x0, y0, (kc + 1) * 32);

        const bf16* sb = slab + (size_t)cur * SLAB;
#pragma unroll
        for (int t = 0; t < 9; ++t) {
            const int dy = t / 3 - 1, dx = t % 3 - 1;
#pragma unroll
            for (int ks = 0; ks < 2; ++ks) {
                short8 a[4];
#pragma unroll
                for (int mt = 0; mt < 4; ++mt) {
                    const int srow = 2 * rg + (mt >> 1) + dy + 1;      // 0..5
                    const int px   = (mt & 1) * 32 + ln31 + dx + 1;    // 0..65
                    const int slot = (ks * 2 + oct) ^ ((px >> 1) & 3);
                    a[mt] = *(const short8*)(sb + (srow * 66 + px) * 32 + slot * 8);
                }
#pragma unroll
                for (int nt = 0; nt < NTT; ++nt) {
                    const int gnt = ng * NTT + nt;
                    short8 bfr = *(const short8*)(wrb
                        + ((size_t)((((kc * 9 + t) * 2 + ks) * NTOT + gnt) * 64 + lane)) * 8);
#pragma unroll
                    for (int mt = 0; mt < 4; ++mt)
                        acc[mt][nt] = __builtin_amdgcn_mfma_f32_32x32x16_bf16(
                                          a[mt], bfr, acc[mt][nt], 0, 0, 0);
                }
            }
        }
        cur ^= 1;
    }

    // Epilogue. 32x32 C/D: col(co) = lane&31, row(px) = (j&3)+8*(j>>2)+4*oct.
#pragma unroll
    for (int nt = 0; nt < NTT; ++nt) {
        const int co = (ng * NTT + nt) * 32 + ln31;
        const float bb = bias[co];
#pragma unroll
        for (int mt = 0; mt < 4; ++mt) {
            const int r  = 2 * rg + (mt >> 1);
            const int xb = x0 + (mt & 1) * 32;
#pragma unroll
            for (int j = 0; j < 16; ++j) {
                const int m = (j & 3) + 8 * (j >> 2) + 4 * oct;
                const float v = fmaxf(acc[mt][nt][j] + bb, 0.0f);
                out_i[((size_t)(y0 + r) * WW + (xb + m)) * COUT + co] = __float2bfloat16(v);
            }
        }
    }
}

// ---------------------------------------------------------------------------
// conv v13 (COUT=64 layers, measured good): dy-reuse full af[4][2] cache.
// ---------------------------------------------------------------------------
template<int CIN, int COUT, int WPB>
__global__ __launch_bounds__(256, WPB) void conv_mfma_v13(const bf16* __restrict__ in,
                                                          const bf16* __restrict__ wrb,
                                                          const float* __restrict__ bias,
                                                          bf16* __restrict__ out)
{
    constexpr int NCH  = CIN / 32;
    constexpr int NTT  = COUT / 64;          // 1 for COUT=64
    constexpr int NTOT = COUT / 32;
    constexpr int SLAB = 6 * 66 * 32;
    __shared__ bf16 slab[2 * SLAB];

    const int tid  = threadIdx.x;
    const int lane = tid & 63;
    const int wv   = tid >> 6;
    const int ng   = wv & 1;
    const int rg   = wv >> 1;
    const int ln31 = lane & 31;
    const int oct  = lane >> 5;
    const int img  = blockIdx.y >> 6;
    const int x0   = blockIdx.x * 64;
    const int y0   = (blockIdx.y & 63) * 4;

    const bf16* in_i  = in  + (size_t)img * HW * CIN;
    bf16*       out_i = out + (size_t)img * HW * COUT;

    f32x16 acc[4][NTT];
#pragma unroll
    for (int mt = 0; mt < 4; ++mt)
#pragma unroll
        for (int nt = 0; nt < NTT; ++nt)
#pragma unroll
            for (int j = 0; j < 16; ++j) acc[mt][nt][j] = 0.0f;

    zero_oob<4, 256>(slab, slab + SLAB, tid, x0, y0);
    stage_async<CIN, 4, 256>(in_i, slab, tid, x0, y0, 0);

    int cur = 0;
    for (int kc = 0; kc < NCH; ++kc) {
        __syncthreads();
        if (kc + 1 < NCH)
            stage_async<CIN, 4, 256>(in_i, slab + (size_t)(cur ^ 1) * SLAB,
                                     tid, x0, y0, (kc + 1) * 32);

        const bf16* sb = slab + (size_t)cur * SLAB;
#pragma unroll
        for (int dxi = 0; dxi < 3; ++dxi) {
            const int dx = dxi - 1;
#pragma unroll
            for (int ks = 0; ks < 2; ++ks) {
                short8 af[4][2];             // [srow offset][x-half]
#pragma unroll
                for (int s = 0; s < 4; ++s)
#pragma unroll
                    for (int mx = 0; mx < 2; ++mx) {
                        const int px   = mx * 32 + ln31 + dx + 1;
                        const int slot = (ks * 2 + oct) ^ ((px >> 1) & 3);
                        af[s][mx] = *(const short8*)(sb + ((2 * rg + s) * 66 + px) * 32 + slot * 8);
                    }
#pragma unroll
                for (int dyi = 0; dyi < 3; ++dyi) {
                    const int t = dyi * 3 + dxi;
#pragma unroll
                    for (int nt = 0; nt < NTT; ++nt) {
                        const int gnt = ng * NTT + nt;
                        short8 bfr = *(const short8*)(wrb
                            + ((size_t)((((kc * 9 + t) * 2 + ks) * NTOT + gnt) * 64 + lane)) * 8);
#pragma unroll
                        for (int mt = 0; mt < 4; ++mt)
                            acc[mt][nt] = __builtin_amdgcn_mfma_f32_32x32x16_bf16(
                                              af[(mt >> 1) + dyi][mt & 1], bfr, acc[mt][nt], 0, 0, 0);
                    }
                }
            }
        }
        cur ^= 1;
    }

#pragma unroll
    for (int nt = 0; nt < NTT; ++nt) {
        const int co = (ng * NTT + nt) * 32 + ln31;
        const float bb = bias[co];
#pragma unroll
        for (int mt = 0; mt < 4; ++mt) {
            const int r  = 2 * rg + (mt >> 1);
            const int xb = x0 + (mt & 1) * 32;
#pragma unroll
            for (int j = 0; j < 16; ++j) {
                const int m = (j & 3) + 8 * (j >> 2) + 4 * oct;
                const float v = fmaxf(acc[mt][nt][j] + bb, 0.0f);
                out_i[((size_t)(y0 + r) * WW + (xb + m)) * COUT + co] = __float2bfloat16(v);
            }
        }
    }
}

// ---------------------------------------------------------------------------
// Merged heads: dbuf DMA staging, both kh and kv; lane-major coalesced B;
// per-pixel softmax over 11 channels via wave-private padded LDS transpose.
// ---------------------------------------------------------------------------
__global__ __launch_bounds__(256, 2) void head_mfma2(const bf16* __restrict__ in,
                                                     const bf16* __restrict__ wrp,
                                                     const float* __restrict__ bh,
                                                     const float* __restrict__ bv,
                                                     float* __restrict__ kh_base,
                                                     float* __restrict__ kv_base,
                                                     int b0)
{
    constexpr int SLABH = 6 * 66 * 32;
    __shared__ bf16  slab[2 * SLABH];       // 50,688 B
    __shared__ float smx[4][64][17];        // 17,408 B (wave-private slices)

    const int tid  = threadIdx.x;
    const int lane = tid & 63;
    const int wv   = tid >> 6;
    const int m    = lane & 15;
    const int q    = lane >> 4;
    const int img  = blockIdx.y >> 6;
    const int x0   = blockIdx.x * 64;
    const int y0   = (blockIdx.y & 63) * 4;
    const int y    = y0 + wv;

    const bf16* in_i = in + (size_t)img * HW * 64;

    f32x4 acc[4][2];
#pragma unroll
    for (int f = 0; f < 4; ++f) { acc[f][0] = (f32x4){0.f,0.f,0.f,0.f}; acc[f][1] = (f32x4){0.f,0.f,0.f,0.f}; }

    zero_oob<4, 256>(slab, slab + SLABH, tid, x0, y0);
    stage_async<64, 4, 256>(in_i, slab, tid, x0, y0, 0);

    int cur = 0;
    for (int kc = 0; kc < 2; ++kc) {
        __syncthreads();
        if (kc == 0)
            stage_async<64, 4, 256>(in_i, slab + SLABH, tid, x0, y0, 32);

        const bf16* sb = slab + (size_t)cur * SLABH;
#pragma unroll
        for (int t = 0; t < 9; ++t) {
            const int dy = t / 3 - 1, dx = t % 3 - 1;
            const int srow = wv + dy + 1;
            short8 b0f = *(const short8*)(wrp + ((size_t)(((kc * 9 + t) * 2 + 0) * 64 + lane)) * 8);
            short8 b1f = *(const short8*)(wrp + ((size_t)(((kc * 9 + t) * 2 + 1) * 64 + lane)) * 8);
#pragma unroll
            for (int f = 0; f < 4; ++f) {
                const int px = f * 16 + m + dx + 1;
                const int slot = q ^ ((px >> 1) & 3);
                short8 a = *(const short8*)(sb + (srow * 66 + px) * 32 + slot * 8);
                acc[f][0] = __builtin_amdgcn_mfma_f32_16x16x32_bf16(a, b0f, acc[f][0], 0, 0, 0);
                acc[f][1] = __builtin_amdgcn_mfma_f32_16x16x32_bf16(a, b1f, acc[f][1], 0, 0, 0);
            }
        }
        cur ^= 1;
    }

    // two heads sequentially; smx slice is wave-private (no barrier needed)
#pragma unroll
    for (int head = 0; head < 2; ++head) {
        const float* bias = head ? bv : bh;
        const float bb = (m < 11) ? bias[m] : 0.0f;
#pragma unroll
        for (int f = 0; f < 4; ++f)
#pragma unroll
            for (int r = 0; r < 4; ++r)
                smx[wv][f * 16 + q * 4 + r][m] = acc[f][head][r] + bb;

        float v[11];
#pragma unroll
        for (int j = 0; j < 11; ++j) v[j] = smx[wv][lane][j];
        float mx = v[0];
#pragma unroll
        for (int j = 1; j < 11; ++j) mx = fmaxf(mx, v[j]);
        float s = 0.0f;
#pragma unroll
        for (int j = 0; j < 11; ++j) { v[j] = expf(v[j] - mx); s += v[j]; }
        const float inv = 1.0f / s;

        float* op = (head ? kv_base : kh_base) + (size_t)(b0 + img) * 11 * HW
                    + (size_t)y * WW + x0 + lane;
#pragma unroll
        for (int j = 0; j < 11; ++j)
            op[(size_t)j * HW] = v[j] * inv;
    }
}

// ---------------------------------------------------------------------------
// Horizontal separable pass (full batch): h = sum_i kh_i * shift_x(rgb, i-5)
// ---------------------------------------------------------------------------
__global__ __launch_bounds__(256) void hpass(const float* __restrict__ rgb,
                                             const float* __restrict__ kh,
                                             float* __restrict__ h)
{
    int idx = blockIdx.x * 256 + threadIdx.x;     // b*HW + p, total 524288
    int b = idx >> 16;                            // HW = 2^16
    int p = idx & (HW - 1);
    int y = p >> 8;
    int x = p & 255;

    float kw[11];
#pragma unroll
    for (int i = 0; i < 11; ++i) kw[i] = kh[((size_t)(b * 11 + i)) * HW + p];

#pragma unroll
    for (int c = 0; c < 3; ++c) {
        const float* rp = rgb + ((size_t)(b * 3 + c)) * HW + (size_t)y * WW;
        float s = 0.0f;
#pragma unroll
        for (int i = 0; i < 11; ++i) {
            int xx = x + i - 5;
            if (xx >= 0 && xx < WW) s = fmaf(kw[i], rp[xx], s);
        }
        h[((size_t)(b * 3 + c)) * HW + p] = s;
    }
}

// ---------------------------------------------------------------------------
// Vertical pass + depth-mask composite. Writes final, blurred, mask.
// ---------------------------------------------------------------------------
__global__ __launch_bounds__(256) void vpass_compose(const float* __restrict__ h,
                                                     const float* __restrict__ kv,
                                                     const float* __restrict__ rgb,
                                                     const float* __restrict__ depth,
                                                     float* __restrict__ fin,
                                                     float* __restrict__ blur,
                                                     float* __restrict__ masko)
{
    int idx = blockIdx.x * 256 + threadIdx.x;
    int b = idx >> 16;                            // HW = 2^16
    int p = idx & (HW - 1);
    int y = p >> 8;
    int x = p & 255;

    float kw[11];
#pragma unroll
    for (int i = 0; i < 11; ++i) kw[i] = kv[((size_t)(b * 11 + i)) * HW + p];

    float d = depth[idx];
    float mk = (d > 0.2f) ? 1.0f : 0.0f;
    masko[idx] = mk;

#pragma unroll
    for (int c = 0; c < 3; ++c) {
        const float* hp = h + ((size_t)(b * 3 + c)) * HW + x;
        float s = 0.0f;
#pragma unroll
        for (int i = 0; i < 11; ++i) {
            int yy = y + i - 5;
            if (yy >= 0 && yy < HH) s = fmaf(kw[i], hp[(size_t)yy * WW], s);
        }
        size_t o = ((size_t)(b * 3 + c)) * HW + p;
        blur[o] = s;
        fin[o] = mk * rgb[o] + (1.0f - mk) * s;
    }
}

// ---------------------------------------------------------------------------
extern "C" void kernel_launch(void* const* d_in, const int* in_sizes, int n_in,
                              void* d_out, int out_size, void* d_ws, size_t ws_size,
                              hipStream_t stream)
{
    const float* rgb   = (const float*)d_in[0];
    const float* depth = (const float*)d_in[1];
    const float* w1 = (const float*)d_in[2];  const float* b1 = (const float*)d_in[3];
    const float* w2 = (const float*)d_in[4];  const float* b2 = (const float*)d_in[5];
    const float* w3 = (const float*)d_in[6];  const float* b3 = (const float*)d_in[7];
    const float* w4 = (const float*)d_in[8];  const float* b4 = (const float*)d_in[9];
    const float* w5 = (const float*)d_in[10]; const float* b5 = (const float*)d_in[11];
    const float* wh = (const float*)d_in[12]; const float* bh = (const float*)d_in[13];
    const float* wv = (const float*)d_in[14]; const float* bv = (const float*)d_in[15];

    float* out    = (float*)d_out;
    float* fin_o  = out;                    // [8,3,256,256]
    float* blur_o = out + 1572864;          // [8,3,256,256]
    float* kh_o   = out + 3145728;          // [8,11,256,256]
    float* kv_o   = out + 8912896;          // [8,11,256,256]
    float* mask_o = out + 14680064;         // [8,1,256,256]

    // --- Select batch group size G from ws_size (deterministic -> graph-safe).
    const size_t perG = (size_t)HW * 2 * (128 + 64 + 128);   // 41.9 MB per image
    const size_t wsz  = (size_t)1 * 1024 * 1024;
    int G = 1;
    if (ws_size >= 8 * perG + wsz) G = 8;
    else if (ws_size >= 4 * perG + wsz) G = 4;
    else if (ws_size >= 2 * perG + wsz) G = 2;

    char* ws = (char*)d_ws;
    const size_t szA = (size_t)G * HW * 128 * 2;
    const size_t szB = (size_t)G * HW * 64 * 2;
    const size_t szC = (size_t)G * HW * 128 * 2;
    bf16* bufA = (bf16*)ws;
    bf16* bufB = (bf16*)(ws + szA);
    bf16* bufC = (bf16*)(ws + szA + szB);
    float* hbuf = (float*)bufC;              // 6.3 MB <= szC (post-loop only)
    bf16*  p8   = (bf16*)bufC;               // pad8 aliases bufC: only live
                                             // during conv1, before conv3 writes
                                             // (G*PHW2*8*2 = 4.3 MB << szC)

    bf16* w2r  = (bf16*)(ws + szA + szB + szC);
    bf16* w3r  = w2r + 9 * 64 * 64;
    bf16* w4r  = w3r + 9 * 128 * 64;
    bf16* w5r  = w4r + 9 * 128 * 128;
    bf16* whvr = w5r + 9 * 64 * 128;         // [2][9][2][64][8] lane-major
    bf16* w1r  = whvr + 18432;               // [5][2][64][8] conv1 mfma

    dim3 blk(256);

    // one-time weight reorders (graph-safe: identical work every call)
    reorder_w_cl<64, 64>  <<<dim3((9*64*64   + 255) / 256), blk, 0, stream>>>(w2, w2r);
    reorder_w_cl<128, 64> <<<dim3((9*128*64  + 255) / 256), blk, 0, stream>>>(w3, w3r);
    reorder_w_cl<128, 128><<<dim3((9*128*128 + 255) / 256), blk, 0, stream>>>(w4, w4r);
    reorder_w_cl<64, 128> <<<dim3((9*64*128  + 255) / 256), blk, 0, stream>>>(w5, w5r);
    reorder_w_head2_lm    <<<dim3((18432     + 255) / 256), blk, 0, stream>>>(wh, wv, whvr);
    reorder_w1_mfma       <<<dim3((5120      + 255) / 256), blk, 0, stream>>>(w1, w1r);

    for (int b0 = 0; b0 < BB; b0 += G) {
        // conv1: pad8 pre-pass + MFMA conv (bufC region free here).
        pad8_rgbd <<<dim3((G * PHW2 + 255) / 256), blk, 0, stream>>>(rgb, depth, p8, b0, G);
        conv1_mfma<<<dim3(4, 64 * G), blk, 0, stream>>>(p8, w1r, b1, bufA);
        // COUT=64: v13 (dy-reuse cache); COUT=128: v12 (747.7us-verified).
        conv_mfma_v13<64, 64, 3>  <<<dim3(4, 64 * G), blk, 0, stream>>>(bufA, w2r, b2, bufB);
        conv_mfma_v12<64, 128, 2> <<<dim3(4, 64 * G), blk, 0, stream>>>(bufB, w3r, b3, bufC);
        conv_mfma_v12<128, 128, 2><<<dim3(4, 64 * G), blk, 0, stream>>>(bufC, w4r, b4, bufA);
        conv_mfma_v13<128, 64, 3> <<<dim3(4, 64 * G), blk, 0, stream>>>(bufA, w5r, b5, bufB);
        head_mfma2<<<dim3(4, 64 * G), blk, 0, stream>>>(bufB, whvr, bh, bv, kh_o, kv_o, b0);
    }

    // separable blur + composite (full batch; bufC conv use dead by now)
    hpass<<<dim3(2048), blk, 0, stream>>>(rgb, kh_o, hbuf);
    vpass_compose<<<dim3(2048), blk, 0, stream>>>(hbuf, kv_o, rgb, depth,
                                                  fin_o, blur_o, mask_o);
}